// Round 11
// baseline (83.017 us; speedup 1.0000x reference)
//
#include <hip/hip_runtime.h>
#include <math.h>

#define LSEQ 512
#define EDIM 256
#define PDIM 2048
#define BM   128
#define BK   32
#define NT   16      // K-steps = LSEQ/BK

typedef _Float16 f16x8 __attribute__((ext_vector_type(8)));
typedef _Float16 f16x2 __attribute__((ext_vector_type(2)));
typedef float    f32x4 __attribute__((ext_vector_type(4)));

#if __has_builtin(__builtin_amdgcn_exp2f)
#define EXP2F(x) __builtin_amdgcn_exp2f(x)
#else
#define EXP2F(x) __expf((x) * 0.6931471805599453f)
#endif

__device__ inline f16x2 pk2(float a, float b) {
#if __has_builtin(__builtin_amdgcn_cvt_pkrtz)
    return __builtin_bit_cast(f16x2, __builtin_amdgcn_cvt_pkrtz(a, b));
#else
    f16x2 r; r[0] = (_Float16)a; r[1] = (_Float16)b; return r;
#endif
}

__device__ inline float hw_sin(float ang) {
#if __has_builtin(__builtin_amdgcn_sinf)
    float rev = ang * 0.15915494309189535f;
    return __builtin_amdgcn_sinf(rev - floorf(rev));
#else
    return sinf(ang);
#endif
}
__device__ inline float hw_cos(float ang) {
#if __has_builtin(__builtin_amdgcn_cosf)
    float rev = ang * 0.15915494309189535f;
    return __builtin_amdgcn_cosf(rev - floorf(rev));
#else
    return cosf(ang);
#endif
}

// Conflict-balanced interleaved tile layout (fp16 element offset) for a
// [rows][32] fp16 tile stored as 128B row-pairs. r = row, g = k-group (0..3).
__device__ __host__ inline int tile_off(int r, int g) {
    return ((r >> 1) << 6) + ((r & 1) << 5) + (((g ^ ((r >> 1) & 3)) & 3) << 3);
}

__device__ inline void g2lds16(const void* g, void* l) {
    __builtin_amdgcn_global_load_lds(
        (const __attribute__((address_space(1))) void*)g,
        (__attribute__((address_space(3))) void*)l, 16, 0, 0);
}

// ---- per-batch bitonic sort of 2048 positions (ascending) + orig index ----
__global__ __launch_bounds__(1024) void sort_pos(const float* __restrict__ cpos,
                                                 float* __restrict__ spos,
                                                 int*   __restrict__ oidx) {
    const int b = blockIdx.x, tid = threadIdx.x;
    __shared__ float v[2048];
    __shared__ int   ix[2048];
    v[tid] = cpos[b * PDIM + tid];           ix[tid] = tid;
    v[tid + 1024] = cpos[b * PDIM + tid + 1024]; ix[tid + 1024] = tid + 1024;
    for (int k = 2; k <= 2048; k <<= 1) {
        for (int j = k >> 1; j > 0; j >>= 1) {
            __syncthreads();
#pragma unroll
            for (int r = 0; r < 2; ++r) {
                const int i = tid + (r << 10);
                const int p = i ^ j;
                if (p > i) {
                    const bool up = ((i & k) == 0);
                    const float a = v[i], c = v[p];
                    if ((a > c) == up) {
                        v[i] = c; v[p] = a;
                        const int t2 = ix[i]; ix[i] = ix[p]; ix[p] = t2;
                    }
                }
            }
        }
    }
    __syncthreads();
    spos[b * PDIM + tid] = v[tid];           oidx[b * PDIM + tid] = ix[tid];
    spos[b * PDIM + tid + 1024] = v[tid + 1024]; oidx[b * PDIM + tid + 1024] = ix[tid + 1024];
}

// ---- fused precompute: baset chunk + params + per-(b,t) l-block envelope ---
__global__ __launch_bounds__(256) void precompute_all(
    const int*   __restrict__ bs,      // (B, L)
    const float* __restrict__ ls,      // (256, 3)
    const float* __restrict__ emb,     // (256, E)
    float2*      __restrict__ params,  // (B, L) {c2*log2e, log2(amp)}
    float2*      __restrict__ benv,    // (B, NT) {lo, hi} active envelope
    _Float16*    __restrict__ baset) { // (B*NT) chunks of 16 KB
    const int b   = blockIdx.x >> 4;
    const int t   = blockIdx.x & 15;
    const int tid = threadIdx.x;       // = e (0..255)

    __shared__ int sByte[BK];
    __shared__ float sLo[BK], sHi[BK];
    if (tid < BK) {
        const int l    = t * BK + tid;
        const int byte = bs[b * LSEQ + l];
        sByte[tid] = byte;
        const float l1  = ls[byte * 3 + 1];
        const float l2  = ls[byte * 3 + 2];
        const float wdt = fabsf(l1) * 0.02f + 1e-5f;
        const float amp = 1.0f / (1.0f + __expf(-l2));
        const float la  = __log2f(amp);
        params[b * LSEQ + l] = make_float2(-0.72134752f / (wdt * wdt), la);
        // cutoff radius: amp * 2^(d^2*c2) < 1e-5  =>  d > wdt*sqrt((la+16.61)/0.7213)
        const float dcut = wdt * sqrtf((la + 16.6096f) * (1.0f / 0.72134752f));
        const float ctr  = (float)l * (1.0f / (float)(LSEQ - 1));
        sLo[tid] = ctr - dcut;
        sHi[tid] = ctr + dcut;
    }
    __syncthreads();
    if (tid == 0) {
        float lo = sLo[0], hi = sHi[0];
#pragma unroll
        for (int i = 1; i < BK; ++i) { lo = fminf(lo, sLo[i]); hi = fmaxf(hi, sHi[i]); }
        benv[blockIdx.x] = make_float2(lo, hi);
    }

    // PE dim e: pair index e>>1, phase e&1 (0=sin, 1=cos)
    const float div = __expf((float)(tid >> 1) * (-2.0f * 9.210340372f / 256.0f));
    _Float16* chunk = baset + ((size_t)blockIdx.x << 13);
#pragma unroll
    for (int g = 0; g < 4; ++g) {
        f16x8 v;
#pragma unroll
        for (int j = 0; j < 8; ++j) {
            const int lj  = g * 8 + j;
            const float ang = (float)(t * BK + lj) * div;
            const float pev = (tid & 1) ? hw_cos(ang) : hw_sin(ang);
            v[j] = (_Float16)(emb[sByte[lj] * EDIM + tid] + pev);
        }
        *(f16x8*)&chunk[tile_off(tid, g)] = v;
    }
}

// ----------------------------- MFMA field kernel ----------------------------
// R6 structure (512 thr, 8 waves 2x4, 16x16x32 f16, BK=32, 2-phase dbuf)
// + sorted positions + wave-uniform l-block skip + index-gather epilogue.
__global__ __launch_bounds__(512, 4) void field_mfma(
    const float*    __restrict__ spos,    // (B,P) sorted positions
    const int*      __restrict__ oidx,    // (B,P) original index per sorted slot
    const float2*   __restrict__ params,  // (B,L) {c2*log2e, log2(amp)}
    const float2*   __restrict__ benv,    // (B,NT) envelopes
    const _Float16* __restrict__ baset,   // pre-swizzled BASE^T chunks
    float*          __restrict__ out) {   // (B,P,E)

    __shared__ __align__(16) _Float16 sW[2][BM * BK];    // 2 x 8 KB
    __shared__ __align__(16) _Float16 sB[2][EDIM * BK];  // 2 x 16 KB
    __shared__ __align__(16) float2   sPrm[LSEQ];        // 4 KB
    __shared__ float  sPos[BM];
    __shared__ int    sIdx[BM];
    __shared__ float2 sBenv[NT];

    const int orig = blockIdx.x;
    const int wg   = (orig & 7) * 128 + (orig >> 3);     // bijective XCD swizzle
    const int b    = wg >> 4;
    const int pt   = wg & 15;

    const int tid = threadIdx.x, lane = tid & 63, wave = tid >> 6;
    const int c15 = lane & 15, g4 = lane >> 4;
    const int wrow = wave >> 2, wcol = wave & 3;         // 2 x 4 wave grid

    const int sp = tid >> 2;       // genW: p row (0..127)
    const int sg = tid & 3;        // genW: k-group of 8
    const float invL = 1.0f / (float)(LSEQ - 1);
    const int woff = tile_off(sp, sg);

    int aoff[4], boff[4];
#pragma unroll
    for (int rt = 0; rt < 4; ++rt) aoff[rt] = tile_off(wrow * 64 + rt * 16 + c15, g4);
#pragma unroll
    for (int ct = 0; ct < 4; ++ct) boff[ct] = tile_off(wcol * 64 + ct * 16 + c15, g4);

    // ---- prologue: stage sPrm/sPos/sIdx/sBenv; issue B0,B1 gloads ----
    sPrm[tid] = params[b * LSEQ + tid];
    if (tid < BM) {
        sPos[tid] = spos[b * PDIM + pt * BM + tid];
        sIdx[tid] = oidx[b * PDIM + pt * BM + tid];
    }
    if (tid < NT) sBenv[tid] = benv[b * NT + tid];

    const _Float16* bt = baset + ((size_t)b * NT << 13);
#pragma unroll
    for (int buf = 0; buf < 2; ++buf) {
        const _Float16* src = bt + buf * 8192 + wave * 1024 + lane * 8;
        g2lds16(src,       &sB[buf][wave * 1024]);
        g2lds16(src + 512, &sB[buf][wave * 1024 + 512]);
    }
    __syncthreads();

    const float mypos = sPos[sp];
    const float glo = sPos[wave * 16], ghi = sPos[wave * 16 + 15];   // genW stripe
    const float wlo = sPos[wrow * 64], whi = sPos[wrow * 64 + 63];   // MFMA rows

    // genW for K-step t into sW[dbuf] (stripe-skip -> zeros)
    auto genW = [&](int t, int dbuf) {
        const float2 be = sBenv[t];
        if (ghi < be.x || glo > be.y) {
            *(f16x8*)&sW[dbuf][woff] = (f16x8)(_Float16)0.0f;
            return;
        }
        const float4* qp = (const float4*)&sPrm[t * BK + sg * 8];
        const float4 q0 = qp[0], q1 = qp[1], q2 = qp[2], q3 = qp[3];
        const float bl0 = (float)(t * BK + sg * 8) * invL;
        const float pd  = mypos - bl0;
        float w[8];
#define GW(i, c2, la) { float d = pd - (float)(i) * invL; \
                        w[i] = EXP2F(fmaf(d * d, (c2), (la))); }
        GW(0, q0.x, q0.y) GW(1, q0.z, q0.w)
        GW(2, q1.x, q1.y) GW(3, q1.z, q1.w)
        GW(4, q2.x, q2.y) GW(5, q2.z, q2.w)
        GW(6, q3.x, q3.y) GW(7, q3.z, q3.w)
#undef GW
        f16x8 wv;
        ((f16x2*)&wv)[0] = pk2(w[0], w[1]);
        ((f16x2*)&wv)[1] = pk2(w[2], w[3]);
        ((f16x2*)&wv)[2] = pk2(w[4], w[5]);
        ((f16x2*)&wv)[3] = pk2(w[6], w[7]);
        *(f16x8*)&sW[dbuf][woff] = wv;
    };

    genW(0, 0);
    __syncthreads();

    f32x4 acc[4][4];
#pragma unroll
    for (int i = 0; i < 4; ++i)
#pragma unroll
        for (int j = 0; j < 4; ++j) acc[i][j] = (f32x4)(0.f);

    // ---- main loop: one barrier per K-step ----
    for (int t = 0; t < NT; ++t) {
        const int cur = t & 1;
        if (t < NT - 1) genW(t + 1, cur ^ 1);   // spare buffer, no hazard

        {   // MFMA cluster, wave-uniform skip vs this block's envelope
            const float2 be = sBenv[t];
            if (!(whi < be.x || wlo > be.y)) {
                const _Float16* wb = sW[cur];
                const _Float16* bb = sB[cur];
                f16x8 af[4];
#pragma unroll
                for (int rt = 0; rt < 4; ++rt) af[rt] = *(const f16x8*)&wb[aoff[rt]];
                __builtin_amdgcn_s_setprio(1);
#pragma unroll
                for (int ct = 0; ct < 4; ++ct) {
                    const f16x8 bf = *(const f16x8*)&bb[boff[ct]];
#pragma unroll
                    for (int rt = 0; rt < 4; ++rt)
                        acc[rt][ct] = __builtin_amdgcn_mfma_f32_16x16x32_f16(af[rt], bf, acc[rt][ct], 0, 0, 0);
                }
                __builtin_amdgcn_s_setprio(0);
            }
        }

        __syncthreads();   // drains W[t+1] ds_writes + B[t+1] stage gloads

        if (t < NT - 2) {  // issue B[t+2] into the buffer just freed
            const _Float16* src = bt + (t + 2) * 8192 + wave * 1024 + lane * 8;
            g2lds16(src,       &sB[cur][wave * 1024]);
            g2lds16(src + 512, &sB[cur][wave * 1024 + 512]);
        }
    }

    // ---- epilogue: C/D col=lane&15 (e), row=g4*4+reg (p); gather orig p ----
#pragma unroll
    for (int rt = 0; rt < 4; ++rt) {
        int op_[4];
#pragma unroll
        for (int reg = 0; reg < 4; ++reg)
            op_[reg] = sIdx[wrow * 64 + rt * 16 + g4 * 4 + reg];
#pragma unroll
        for (int ct = 0; ct < 4; ++ct) {
            const int e = wcol * 64 + ct * 16 + c15;
#pragma unroll
            for (int reg = 0; reg < 4; ++reg)
                out[((size_t)b * PDIM + op_[reg]) * EDIM + e] = acc[rt][ct][reg];
        }
    }
}

extern "C" void kernel_launch(void* const* d_in, const int* in_sizes, int n_in,
                              void* d_out, int out_size, void* d_ws, size_t ws_size,
                              hipStream_t stream) {
    const int*   bs   = (const int*)d_in[0];
    const float* cpos = (const float*)d_in[1];
    const float* emb  = (const float*)d_in[2];
    const float* ls   = (const float*)d_in[3];

    const int B = in_sizes[0] / LSEQ;   // 64

    char* ws = (char*)d_ws;
    float2*   params = (float2*)ws;                       // 256 KB @ 0
    float*    spos   = (float*)(ws + 0x40000);            // 512 KB
    int*      oidx   = (int*)(ws + 0xC0000);              // 512 KB
    float2*   benv   = (float2*)(ws + 0x140000);          // 8 KB
    _Float16* baset  = (_Float16*)(ws + 0x180000);        // 16 MB

    sort_pos<<<B, 1024, 0, stream>>>(cpos, spos, oidx);
    precompute_all<<<B * NT, 256, 0, stream>>>(bs, ls, emb, params, benv, baset);
    field_mfma<<<B * (PDIM / BM), 512, 0, stream>>>(spos, oidx, params, benv, baset,
                                                    (float*)d_out);
}

// Round 13
// 72.954 us; speedup vs baseline: 1.1379x; 1.1379x over previous
//
#include <hip/hip_runtime.h>
#include <math.h>

#define LSEQ 512
#define EDIM 256
#define PDIM 2048
#define BM   128
#define BK   32
#define NT   16      // K-steps = LSEQ/BK

typedef _Float16 f16x8 __attribute__((ext_vector_type(8)));
typedef _Float16 f16x2 __attribute__((ext_vector_type(2)));
typedef float    f32x4 __attribute__((ext_vector_type(4)));

#if __has_builtin(__builtin_amdgcn_exp2f)
#define EXP2F(x) __builtin_amdgcn_exp2f(x)
#else
#define EXP2F(x) __expf((x) * 0.6931471805599453f)
#endif

__device__ inline f16x2 pk2(float a, float b) {
#if __has_builtin(__builtin_amdgcn_cvt_pkrtz)
    return __builtin_bit_cast(f16x2, __builtin_amdgcn_cvt_pkrtz(a, b));
#else
    f16x2 r; r[0] = (_Float16)a; r[1] = (_Float16)b; return r;
#endif
}

__device__ inline float hw_sin(float ang) {
#if __has_builtin(__builtin_amdgcn_sinf)
    float rev = ang * 0.15915494309189535f;
    return __builtin_amdgcn_sinf(rev - floorf(rev));
#else
    return sinf(ang);
#endif
}
__device__ inline float hw_cos(float ang) {
#if __has_builtin(__builtin_amdgcn_cosf)
    float rev = ang * 0.15915494309189535f;
    return __builtin_amdgcn_cosf(rev - floorf(rev));
#else
    return cosf(ang);
#endif
}

// Conflict-balanced interleaved tile layout (fp16 element offset) for a
// [rows][32] fp16 tile stored as 128B row-pairs. r = row, g = k-group (0..3).
__device__ __host__ inline int tile_off(int r, int g) {
    return ((r >> 1) << 6) + ((r & 1) << 5) + (((g ^ ((r >> 1) & 3)) & 3) << 3);
}

__device__ inline void g2lds16(const void* g, void* l) {
    __builtin_amdgcn_global_load_lds(
        (const __attribute__((address_space(1))) void*)g,
        (__attribute__((address_space(3))) void*)l, 16, 0, 0);
}

// ---- fused precompute: one block per (b, k-step) baset chunk ---------------
// Also writes params[b, l] = {-0.5/w^2 * log2e, log2(amp)} for its 32 l's.
__global__ __launch_bounds__(256) void precompute_all(
    const int*   __restrict__ bs,      // (B, L)
    const float* __restrict__ ls,      // (256, 3)
    const float* __restrict__ emb,     // (256, E)
    float2*      __restrict__ params,  // (B, L)
    _Float16*    __restrict__ baset) { // (B*NT) chunks of 16 KB
    const int b   = blockIdx.x >> 4;
    const int t   = blockIdx.x & 15;
    const int tid = threadIdx.x;       // = e (0..255)

    __shared__ int sByte[BK];
    if (tid < BK) {
        const int l    = t * BK + tid;
        const int byte = bs[b * LSEQ + l];
        sByte[tid] = byte;
        const float l1  = ls[byte * 3 + 1];
        const float l2  = ls[byte * 3 + 2];
        const float wdt = fabsf(l1) * 0.02f + 1e-5f;
        const float amp = 1.0f / (1.0f + __expf(-l2));
        params[b * LSEQ + l] = make_float2(-0.72134752f / (wdt * wdt),  // -0.5*log2e/w^2
                                           __log2f(amp));
    }
    __syncthreads();

    // PE dim e: pair index e>>1, phase e&1 (0=sin, 1=cos)
    const float div = __expf((float)(tid >> 1) * (-2.0f * 9.210340372f / 256.0f));
    _Float16* chunk = baset + ((size_t)blockIdx.x << 13);
#pragma unroll
    for (int g = 0; g < 4; ++g) {
        f16x8 v;
#pragma unroll
        for (int j = 0; j < 8; ++j) {
            const int lj  = g * 8 + j;
            const float ang = (float)(t * BK + lj) * div;
            const float pev = (tid & 1) ? hw_cos(ang) : hw_sin(ang);
            v[j] = (_Float16)(emb[sByte[lj] * EDIM + tid] + pev);
        }
        *(f16x8*)&chunk[tile_off(tid, g)] = v;
    }
}

// ----------------------------- MFMA field kernel ----------------------------
// R6 structure: 512 thr (8 waves, 2x4). Tile 128p x 256e, wave tile 64p x 64e,
// BK=32, 16 K-steps, 2-phase dbuf, 16x16x32 f16 MFMA.
// ONLY change vs R6: params come from global (L1-broadcast float4 loads,
// prefetched one K-step ahead; barrier's vmcnt(0) drain covers the latency).
__global__ __launch_bounds__(512, 4) void field_mfma(
    const float*    __restrict__ cpos,    // (B,P)
    const float2*   __restrict__ params,  // (B,L) {c2*log2e, log2(amp)}
    const _Float16* __restrict__ baset,   // pre-swizzled BASE^T chunks
    float*          __restrict__ out) {   // (B,P,E)

    __shared__ __align__(16) _Float16 sW[2][BM * BK];    // 2 x 8 KB
    __shared__ __align__(16) _Float16 sB[2][EDIM * BK];  // 2 x 16 KB

    const int orig = blockIdx.x;
    const int wg   = (orig & 7) * 128 + (orig >> 3);     // bijective XCD swizzle
    const int b    = wg >> 4;
    const int pt   = wg & 15;

    const int tid = threadIdx.x, lane = tid & 63, wave = tid >> 6;
    const int c15 = lane & 15, g4 = lane >> 4;
    const int wrow = wave >> 2, wcol = wave & 3;         // 2 x 4 wave grid

    // W-gen role: thread -> (p row sp, k-group sg of 8 l's)
    const int sp = tid >> 2;
    const int sg = tid & 3;
    const float mypos = cpos[b * PDIM + pt * BM + sp];
    const float invL  = 1.0f / (float)(LSEQ - 1);
    const int   woff  = tile_off(sp, sg);

    // frag read offsets (R6 4x4 16x16 mapping)
    int aoff4[4], boff4[4];
#pragma unroll
    for (int rt = 0; rt < 4; ++rt) aoff4[rt] = tile_off(wrow * 64 + rt * 16 + c15, g4);
#pragma unroll
    for (int ct = 0; ct < 4; ++ct) boff4[ct] = tile_off(wcol * 64 + ct * 16 + c15, g4);

    const float2* prm = params + b * LSEQ;
    const _Float16* bt = baset + ((size_t)b * NT << 13);

    // ---- prologue: issue B0,B1; q(0); genW(0); q(1); barrier ----
#pragma unroll
    for (int buf = 0; buf < 2; ++buf) {
        const _Float16* src = bt + buf * 8192 + wave * 1024 + lane * 8;
        g2lds16(src,       &sB[buf][wave * 1024]);
        g2lds16(src + 512, &sB[buf][wave * 1024 + 512]);
    }

    float4 qn0, qn1, qn2, qn3;   // params for the K-step genW will write next
    {
        const float4* qp = (const float4*)(prm + sg * 8);   // t = 0
        qn0 = qp[0]; qn1 = qp[1]; qn2 = qp[2]; qn3 = qp[3];
    }

    // genW for K-step t into sW[dbuf] using qn0..qn3 (= params for this t)
    auto genW = [&](int t, int dbuf) {
        const float bl0 = (float)(t * BK + sg * 8) * invL;
        const float pd  = mypos - bl0;
        float w[8];
#define GW(i, c2, la) { float d = pd - (float)(i) * invL; \
                        w[i] = EXP2F(fmaf(d * d, (c2), (la))); }
        GW(0, qn0.x, qn0.y) GW(1, qn0.z, qn0.w)
        GW(2, qn1.x, qn1.y) GW(3, qn1.z, qn1.w)
        GW(4, qn2.x, qn2.y) GW(5, qn2.z, qn2.w)
        GW(6, qn3.x, qn3.y) GW(7, qn3.z, qn3.w)
#undef GW
        f16x8 wv;
        ((f16x2*)&wv)[0] = pk2(w[0], w[1]);
        ((f16x2*)&wv)[1] = pk2(w[2], w[3]);
        ((f16x2*)&wv)[2] = pk2(w[4], w[5]);
        ((f16x2*)&wv)[3] = pk2(w[6], w[7]);
        *(f16x8*)&sW[dbuf][woff] = wv;
    };

    genW(0, 0);
    {
        const float4* qp = (const float4*)(prm + BK + sg * 8);  // t = 1
        qn0 = qp[0]; qn1 = qp[1]; qn2 = qp[2]; qn3 = qp[3];
    }
    __syncthreads();   // drains B0/B1 staging + q(1) loads; sW[0] visible

    f32x4 acc[4][4];
#pragma unroll
    for (int i = 0; i < 4; ++i)
#pragma unroll
        for (int j = 0; j < 4; ++j) acc[i][j] = (f32x4)(0.f);

    // ---- main loop: one barrier per K-step (R6 ordering) ----
    for (int t = 0; t < NT; ++t) {
        const int cur = t & 1;
        if (t < NT - 1) genW(t + 1, cur ^ 1);   // spare buffer; uses qn(t+1)

        const _Float16* wb = sW[cur];
        const _Float16* bb = sB[cur];
        f16x8 af[4];
#pragma unroll
        for (int rt = 0; rt < 4; ++rt) af[rt] = *(const f16x8*)&wb[aoff4[rt]];
        __builtin_amdgcn_s_setprio(1);
#pragma unroll
        for (int ct = 0; ct < 4; ++ct) {
            const f16x8 bf = *(const f16x8*)&bb[boff4[ct]];
#pragma unroll
            for (int rt = 0; rt < 4; ++rt)
                acc[rt][ct] = __builtin_amdgcn_mfma_f32_16x16x32_f16(af[rt], bf, acc[rt][ct], 0, 0, 0);
        }
        __builtin_amdgcn_s_setprio(0);

        __syncthreads();   // drains W[t+1] ds_writes + B/q prefetches

        if (t < NT - 2) {  // issue B[t+2] stage + q(t+2) loads (drain next barrier)
            const _Float16* src = bt + (t + 2) * 8192 + wave * 1024 + lane * 8;
            g2lds16(src,       &sB[cur][wave * 1024]);
            g2lds16(src + 512, &sB[cur][wave * 1024 + 512]);
            const float4* qp = (const float4*)(prm + (t + 2) * BK + sg * 8);
            qn0 = qp[0]; qn1 = qp[1]; qn2 = qp[2]; qn3 = qp[3];
        }
    }

    // ---- epilogue: C/D 16x16 layout col=lane&15 (e), row=g4*4+reg (p) ----
#pragma unroll
    for (int rt = 0; rt < 4; ++rt)
#pragma unroll
        for (int ct = 0; ct < 4; ++ct) {
            const int e = wcol * 64 + ct * 16 + c15;
#pragma unroll
            for (int reg = 0; reg < 4; ++reg) {
                const int p = pt * BM + wrow * 64 + rt * 16 + g4 * 4 + reg;
                out[((size_t)b * PDIM + p) * EDIM + e] = acc[rt][ct][reg];
            }
        }
}

extern "C" void kernel_launch(void* const* d_in, const int* in_sizes, int n_in,
                              void* d_out, int out_size, void* d_ws, size_t ws_size,
                              hipStream_t stream) {
    const int*   bs   = (const int*)d_in[0];
    const float* cpos = (const float*)d_in[1];
    const float* emb  = (const float*)d_in[2];
    const float* ls   = (const float*)d_in[3];

    const int B = in_sizes[0] / LSEQ;   // 64

    char* ws = (char*)d_ws;
    float2*   params = (float2*)ws;                   // 256 KB
    _Float16* baset  = (_Float16*)(ws + (1u << 18));  // 16 MB

    precompute_all<<<B * NT, 256, 0, stream>>>(bs, ls, emb, params, baset);
    field_mfma<<<B * (PDIM / BM), 512, 0, stream>>>(cpos, params, baset, (float*)d_out);
}

// Round 14
// 63.445 us; speedup vs baseline: 1.3085x; 1.1499x over previous
//
#include <hip/hip_runtime.h>
#include <math.h>

#define LSEQ 512
#define EDIM 256
#define PDIM 2048
#define BM   128
#define BK   32
#define NT   16      // K-steps = LSEQ/BK

typedef _Float16 f16x8 __attribute__((ext_vector_type(8)));
typedef _Float16 f16x2 __attribute__((ext_vector_type(2)));
typedef float    f32x4 __attribute__((ext_vector_type(4)));

#if __has_builtin(__builtin_amdgcn_exp2f)
#define EXP2F(x) __builtin_amdgcn_exp2f(x)
#else
#define EXP2F(x) __expf((x) * 0.6931471805599453f)
#endif

__device__ inline f16x2 pk2(float a, float b) {
#if __has_builtin(__builtin_amdgcn_cvt_pkrtz)
    return __builtin_bit_cast(f16x2, __builtin_amdgcn_cvt_pkrtz(a, b));
#else
    f16x2 r; r[0] = (_Float16)a; r[1] = (_Float16)b; return r;
#endif
}

__device__ inline float hw_sin(float ang) {
#if __has_builtin(__builtin_amdgcn_sinf)
    float rev = ang * 0.15915494309189535f;
    return __builtin_amdgcn_sinf(rev - floorf(rev));
#else
    return sinf(ang);
#endif
}
__device__ inline float hw_cos(float ang) {
#if __has_builtin(__builtin_amdgcn_cosf)
    float rev = ang * 0.15915494309189535f;
    return __builtin_amdgcn_cosf(rev - floorf(rev));
#else
    return cosf(ang);
#endif
}

// Conflict-balanced interleaved tile layout (fp16 element offset) for a
// [rows][32] fp16 tile stored as 128B row-pairs. r = row, g = k-group (0..3).
// tile_off(r+64,g) = tile_off(r,g) + 2048 (rows 64.. are the second half).
__device__ __host__ inline int tile_off(int r, int g) {
    return ((r >> 1) << 6) + ((r & 1) << 5) + (((g ^ ((r >> 1) & 3)) & 3) << 3);
}

__device__ inline void g2lds16(const void* g, void* l) {
    __builtin_amdgcn_global_load_lds(
        (const __attribute__((address_space(1))) void*)g,
        (__attribute__((address_space(3))) void*)l, 16, 0, 0);
}

// ---- fused precompute: one block per (b, k-step) baset chunk ---------------
// Also writes params[b, l] = {-0.5/w^2 * log2e, log2(amp)} for its 32 l's.
__global__ __launch_bounds__(256) void precompute_all(
    const int*   __restrict__ bs,      // (B, L)
    const float* __restrict__ ls,      // (256, 3)
    const float* __restrict__ emb,     // (256, E)
    float2*      __restrict__ params,  // (B, L)
    _Float16*    __restrict__ baset) { // (B*NT) chunks of 16 KB
    const int b   = blockIdx.x >> 4;
    const int t   = blockIdx.x & 15;
    const int tid = threadIdx.x;       // = e (0..255)

    __shared__ int sByte[BK];
    if (tid < BK) {
        const int l    = t * BK + tid;
        const int byte = bs[b * LSEQ + l];
        sByte[tid] = byte;
        const float l1  = ls[byte * 3 + 1];
        const float l2  = ls[byte * 3 + 2];
        const float wdt = fabsf(l1) * 0.02f + 1e-5f;
        const float amp = 1.0f / (1.0f + __expf(-l2));
        params[b * LSEQ + l] = make_float2(-0.72134752f / (wdt * wdt),  // -0.5*log2e/w^2
                                           __log2f(amp));
    }
    __syncthreads();

    // PE dim e: pair index e>>1, phase e&1 (0=sin, 1=cos)
    const float div = __expf((float)(tid >> 1) * (-2.0f * 9.210340372f / 256.0f));
    _Float16* chunk = baset + ((size_t)blockIdx.x << 13);
#pragma unroll
    for (int g = 0; g < 4; ++g) {
        f16x8 v;
#pragma unroll
        for (int j = 0; j < 8; ++j) {
            const int lj  = g * 8 + j;
            const float ang = (float)(t * BK + lj) * div;
            const float pev = (tid & 1) ? hw_cos(ang) : hw_sin(ang);
            v[j] = (_Float16)(emb[sByte[lj] * EDIM + tid] + pev);
        }
        *(f16x8*)&chunk[tile_off(tid, g)] = v;
    }
}

// ----------------------------- MFMA field kernel ----------------------------
// R6 loop verbatim; block tile 128p x 128e (E split over 2 blocks).
// 512 thr (8 waves, 2x4), wave tile 64p x 32e, acc 4x2 f32x4 = 32 VGPR.
// LDS 36 KB; launch_bounds(512,6) -> target ~24 waves/CU (was ~16).
__global__ __launch_bounds__(512, 6) void field_mfma(
    const float*    __restrict__ cpos,    // (B,P)
    const float2*   __restrict__ params,  // (B,L) {c2*log2e, log2(amp)}
    const _Float16* __restrict__ baset,   // pre-swizzled BASE^T chunks
    float*          __restrict__ out) {   // (B,P,E)

    __shared__ __align__(16) _Float16 sW[2][BM * BK];    // 2 x 8 KB
    __shared__ __align__(16) _Float16 sB[2][128 * BK];   // 2 x 8 KB (E half)
    __shared__ __align__(16) float2   sPrm[LSEQ];        // 4 KB

    const int orig = blockIdx.x;
    const int wg   = (orig & 7) * 256 + (orig >> 3);     // bijective XCD swizzle
    const int b    = wg >> 5;
    const int pt   = (wg >> 1) & 15;
    const int et   = wg & 1;

    const int tid = threadIdx.x, lane = tid & 63, wave = tid >> 6;
    const int c15 = lane & 15, g4 = lane >> 4;
    const int wrow = wave >> 2, wcol = wave & 3;         // 2 x 4 wave grid

    // W-gen role: thread -> (p row sp, k-group sg of 8 l's)  [same as R6]
    const int sp = tid >> 2;
    const int sg = tid & 3;
    const float mypos = cpos[b * PDIM + pt * BM + sp];
    const float invL  = 1.0f / (float)(LSEQ - 1);
    const int   woff  = tile_off(sp, sg);

    // frag read offsets: A rows wrow*64 + rt*16 + c15; B rows wcol*32 + ct*16 + c15
    int aoff4[4], boff2[2];
#pragma unroll
    for (int rt = 0; rt < 4; ++rt) aoff4[rt] = tile_off(wrow * 64 + rt * 16 + c15, g4);
#pragma unroll
    for (int ct = 0; ct < 2; ++ct) boff2[ct] = tile_off(wcol * 32 + ct * 16 + c15, g4);

    // ---- prologue: sPrm -> LDS; issue B0,B1 stage (1 load/thread/buffer) ----
    sPrm[tid] = params[b * LSEQ + tid];
    // chunk = 8192 elements per (b,t); et half = 4096 elements, contiguous
    const _Float16* bt = baset + ((size_t)b * NT << 13) + et * 4096;
#pragma unroll
    for (int buf = 0; buf < 2; ++buf) {
        const _Float16* src = bt + buf * 8192 + wave * 512 + lane * 8;
        g2lds16(src, &sB[buf][wave * 512]);
    }
    __syncthreads();   // sPrm visible (staging drains too; acceptable once)

    // genW for K-step t into sW[dbuf]  [R6 verbatim]
    auto genW = [&](int t, int dbuf) {
        const float4* qp = (const float4*)&sPrm[t * BK + sg * 8];
        const float4 q0 = qp[0], q1 = qp[1], q2 = qp[2], q3 = qp[3];
        const float bl0 = (float)(t * BK + sg * 8) * invL;
        const float pd  = mypos - bl0;
        float w[8];
#define GW(i, c2, la) { float d = pd - (float)(i) * invL; \
                        w[i] = EXP2F(fmaf(d * d, (c2), (la))); }
        GW(0, q0.x, q0.y) GW(1, q0.z, q0.w)
        GW(2, q1.x, q1.y) GW(3, q1.z, q1.w)
        GW(4, q2.x, q2.y) GW(5, q2.z, q2.w)
        GW(6, q3.x, q3.y) GW(7, q3.z, q3.w)
#undef GW
        f16x8 wv;
        ((f16x2*)&wv)[0] = pk2(w[0], w[1]);
        ((f16x2*)&wv)[1] = pk2(w[2], w[3]);
        ((f16x2*)&wv)[2] = pk2(w[4], w[5]);
        ((f16x2*)&wv)[3] = pk2(w[6], w[7]);
        *(f16x8*)&sW[dbuf][woff] = wv;
    };

    genW(0, 0);
    __syncthreads();

    f32x4 acc[4][2];
#pragma unroll
    for (int i = 0; i < 4; ++i)
#pragma unroll
        for (int j = 0; j < 2; ++j) acc[i][j] = (f32x4)(0.f);

    // ---- main loop: one barrier per K-step (R6 ordering) ----
    for (int t = 0; t < NT; ++t) {
        const int cur = t & 1;
        if (t < NT - 1) genW(t + 1, cur ^ 1);   // spare buffer, no hazard

        const _Float16* wb = sW[cur];
        const _Float16* bb = sB[cur];
        f16x8 af[4];
#pragma unroll
        for (int rt = 0; rt < 4; ++rt) af[rt] = *(const f16x8*)&wb[aoff4[rt]];
        __builtin_amdgcn_s_setprio(1);
#pragma unroll
        for (int ct = 0; ct < 2; ++ct) {
            const f16x8 bf = *(const f16x8*)&bb[boff2[ct]];
#pragma unroll
            for (int rt = 0; rt < 4; ++rt)
                acc[rt][ct] = __builtin_amdgcn_mfma_f32_16x16x32_f16(af[rt], bf, acc[rt][ct], 0, 0, 0);
        }
        __builtin_amdgcn_s_setprio(0);

        __syncthreads();   // drains W[t+1] ds_writes + B[t+1] stage gloads

        if (t < NT - 2) {  // issue B[t+2] into the buffer just freed
            const _Float16* src = bt + (t + 2) * 8192 + wave * 512 + lane * 8;
            g2lds16(src, &sB[cur][wave * 512]);
        }
    }

    // ---- epilogue: C/D 16x16 layout col=lane&15 (e), row=g4*4+reg (p) ----
#pragma unroll
    for (int rt = 0; rt < 4; ++rt)
#pragma unroll
        for (int ct = 0; ct < 2; ++ct) {
            const int e = et * 128 + wcol * 32 + ct * 16 + c15;
#pragma unroll
            for (int reg = 0; reg < 4; ++reg) {
                const int p = pt * BM + wrow * 64 + rt * 16 + g4 * 4 + reg;
                out[((size_t)b * PDIM + p) * EDIM + e] = acc[rt][ct][reg];
            }
        }
}

extern "C" void kernel_launch(void* const* d_in, const int* in_sizes, int n_in,
                              void* d_out, int out_size, void* d_ws, size_t ws_size,
                              hipStream_t stream) {
    const int*   bs   = (const int*)d_in[0];
    const float* cpos = (const float*)d_in[1];
    const float* emb  = (const float*)d_in[2];
    const float* ls   = (const float*)d_in[3];

    const int B = in_sizes[0] / LSEQ;   // 64

    char* ws = (char*)d_ws;
    float2*   params = (float2*)ws;                   // 256 KB
    _Float16* baset  = (_Float16*)(ws + (1u << 18));  // 16 MB

    precompute_all<<<B * NT, 256, 0, stream>>>(bs, ls, emb, params, baset);
    const int nblocks = B * (PDIM / BM) * 2;          // 2048
    field_mfma<<<nblocks, 512, 0, stream>>>(cpos, params, baset, (float*)d_out);
}